// Round 10
// baseline (581.386 us; speedup 1.0000x reference)
//
#include <hip/hip_runtime.h>
#include <hip/hip_fp16.h>

// ---------------------------------------------------------------------------
// GNNEncoder: 4x SAGEConv + linear. R9:
//  - fill_xcd: slice selected by PHYSICAL XCD (s_getreg HW_REG_XCC_ID), work
//    pulled from per-slice atomic chunk queues (+stealing for safety).
//    R8 showed scatter targets written from multiple XCDs bounce lines
//    between L2s (~9-18x writeback); blockIdx%8 was NOT the real XCD map.
//  - pack_count: fp32->ushort edge pack fused with degree count (R7).
//  - gather: wave/node, 8 nbr-groups x 8 dim-lanes, fp16 t, fused self+relu.
//  - mm_dual: t(fp16) = h@Wl, u = h@Wr + b one pass; 3-phase scan.
// ---------------------------------------------------------------------------

#define NSLICE 8
#define SCAN_NPB 2048   // nodes per scan block (256 threads x 8)

// pack 2E ints -> 2E ushorts; count degrees for the dst half while packing
__global__ __launch_bounds__(256) void pack_count(
    const int* __restrict__ e32, unsigned short* __restrict__ e16,
    int* __restrict__ cnt, int E)
{
    const int n = 2 * E;
    int i = (blockIdx.x * 256 + threadIdx.x) * 4;
    if (i + 4 <= n) {
        int4 v = *(const int4*)(e32 + i);
        ushort4 p;
        p.x = (unsigned short)v.x; p.y = (unsigned short)v.y;
        p.z = (unsigned short)v.z; p.w = (unsigned short)v.w;
        *(ushort4*)(e16 + i) = p;
        if (i >= E) {                        // whole quad in dst half
            atomicAdd(&cnt[v.x], 1); atomicAdd(&cnt[v.y], 1);
            atomicAdd(&cnt[v.z], 1); atomicAdd(&cnt[v.w], 1);
        } else if (i + 4 > E) {              // straddles the boundary
            if (i + 0 >= E) atomicAdd(&cnt[v.x], 1);
            if (i + 1 >= E) atomicAdd(&cnt[v.y], 1);
            if (i + 2 >= E) atomicAdd(&cnt[v.z], 1);
            if (i + 3 >= E) atomicAdd(&cnt[v.w], 1);
        }
    } else {
        for (; i < n; ++i) {
            int v = e32[i];
            e16[i] = (unsigned short)v;
            if (i >= E) atomicAdd(&cnt[v], 1);
        }
    }
}

// phase 1: per-block sums of cnt
__global__ __launch_bounds__(256) void scan_partial(
    const int* __restrict__ cnt, int* __restrict__ partial, int N)
{
    __shared__ int red[256];
    const int base = blockIdx.x * SCAN_NPB + threadIdx.x * 8;
    int s = 0;
    #pragma unroll
    for (int k = 0; k < 8; ++k) {
        int i = base + k;
        if (i < N) s += cnt[i];
    }
    red[threadIdx.x] = s;
    __syncthreads();
    for (int off = 128; off > 0; off >>= 1) {
        if (threadIdx.x < off) red[threadIdx.x] += red[threadIdx.x + off];
        __syncthreads();
    }
    if (threadIdx.x == 0) partial[blockIdx.x] = red[0];
}

// phase 2: single wave exclusive-scans nb (<=64) partials in place
__global__ __launch_bounds__(64) void scan_partial_scan(int* __restrict__ partial, int nb)
{
    const int lane = threadIdx.x;
    int v = (lane < nb) ? partial[lane] : 0;
    int incl = v;
    #pragma unroll
    for (int off = 1; off < 64; off <<= 1) {
        int o = __shfl_up(incl, off);
        if (lane >= off) incl += o;
    }
    if (lane < nb) partial[lane] = incl - v;   // exclusive
}

// phase 3: local scan + offset -> row_ptr, cursor, inv
__global__ __launch_bounds__(256) void scan_final(
    const int* __restrict__ cnt, const int* __restrict__ partial,
    int* __restrict__ row_ptr, int* __restrict__ cursor,
    float* __restrict__ inv, int N)
{
    __shared__ int sums[256];
    const int tid = threadIdx.x;
    const int base = blockIdx.x * SCAN_NPB + tid * 8;
    int c[8], p = 0;
    #pragma unroll
    for (int k = 0; k < 8; ++k) {
        int i = base + k;
        c[k] = (i < N) ? cnt[i] : 0;
        p += c[k];
    }
    sums[tid] = p;
    __syncthreads();
    for (int off = 1; off < 256; off <<= 1) {
        int v = (tid >= off) ? sums[tid - off] : 0;
        __syncthreads();
        sums[tid] += v;
        __syncthreads();
    }
    int run = partial[blockIdx.x] + ((tid > 0) ? sums[tid - 1] : 0);
    #pragma unroll
    for (int k = 0; k < 8; ++k) {
        int i = base + k;
        if (i < N) {
            row_ptr[i] = run;
            cursor[i]  = run;
            inv[i] = 1.0f / (float)(c[k] > 0 ? c[k] : 1);
            run += c[k];
            if (i == N - 1) row_ptr[N] = run;
        }
    }
}

// fill bound to PHYSICAL XCD: block reads its XCC_ID, pulls chunks of the
// edge stream for the matching slice via per-slice atomic queues; steals
// from other slices once its own is drained (correctness under any dispatch).
__global__ __launch_bounds__(256) void fill_xcd(
    const unsigned short* __restrict__ src, const unsigned short* __restrict__ dst,
    int* __restrict__ cursor, unsigned short* __restrict__ adj,
    int* __restrict__ ctr, int E, int N, int nps, int nchunk)
{
    __shared__ int curc;
    int xcc;
    asm volatile("s_getreg_b32 %0, hwreg(HW_REG_XCC_ID)" : "=s"(xcc));
    const int tid = threadIdx.x;
    for (int off = 0; off < NSLICE; ++off) {
        const int ss = (xcc + off) & (NSLICE - 1);
        const int sbeg = ss * nps;
        const int send = min(sbeg + nps, N);
        for (;;) {
            if (tid == 0) curc = atomicAdd(&ctr[ss], 1);
            __syncthreads();
            const int c = curc;
            __syncthreads();
            if (c >= nchunk) break;
            const int lo = (int)((long long)E * c / nchunk);
            const int hi = (int)((long long)E * (c + 1) / nchunk);
            for (int e = lo + tid; e < hi; e += 256) {
                int d = __builtin_nontemporal_load(dst + e);
                if (d >= sbeg && d < send) {
                    int pos = atomicAdd(&cursor[d], 1);
                    adj[pos] = __builtin_nontemporal_load(src + e);
                }
            }
        }
    }
}

// pull aggregation fused with self-term: out = (relu)(u + inv * sum_j t[adj_j])
// one wave per node: 8 neighbor-groups x 8 dim-lanes, half8 (16B) per lane.
template<bool RELU>
__global__ __launch_bounds__(256) void gather_fused(
    const __half* __restrict__ t, const unsigned short* __restrict__ adj,
    const int* __restrict__ row_ptr, const float* __restrict__ inv,
    const float* __restrict__ u, float* __restrict__ out, int N)
{
    const int node = (blockIdx.x * 256 + threadIdx.x) >> 6;
    const int lane = threadIdx.x & 63;
    const int grp  = lane >> 3;          // 0..7: neighbor slot in the octet
    const int d0   = (lane & 7) * 8;     // dim offset (8 dims per lane)
    if (node >= N) return;
    const int beg = row_ptr[node], end = row_ptr[node + 1];
    float a[8] = {0.f, 0.f, 0.f, 0.f, 0.f, 0.f, 0.f, 0.f};
    int j = beg + grp;
    for (; j + 8 < end; j += 16) {       // 2x unrolled: j and j+8
        const int n0 = adj[j], n1 = adj[j + 8];
        const float4 p0 = *(const float4*)(t + (size_t)n0 * 64 + d0);
        const float4 p1 = *(const float4*)(t + (size_t)n1 * 64 + d0);
        const __half2* h0 = (const __half2*)&p0;
        const __half2* h1 = (const __half2*)&p1;
        #pragma unroll
        for (int k = 0; k < 4; ++k) {
            float2 f0 = __half22float2(h0[k]);
            float2 f1 = __half22float2(h1[k]);
            a[2 * k]     += f0.x + f1.x;
            a[2 * k + 1] += f0.y + f1.y;
        }
    }
    if (j < end) {
        const float4 p0 = *(const float4*)(t + (size_t)adj[j] * 64 + d0);
        const __half2* h0 = (const __half2*)&p0;
        #pragma unroll
        for (int k = 0; k < 4; ++k) {
            float2 f0 = __half22float2(h0[k]);
            a[2 * k]     += f0.x;
            a[2 * k + 1] += f0.y;
        }
    }
    // reduce across the 8 groups (lane bits 3,4,5)
    #pragma unroll
    for (int k = 0; k < 8; ++k) {
        a[k] += __shfl_xor(a[k], 8);
        a[k] += __shfl_xor(a[k], 16);
        a[k] += __shfl_xor(a[k], 32);
    }
    if (grp == 0) {
        const float vi = inv[node];
        const float4 u0 = *(const float4*)(u + (size_t)node * 64 + d0);
        const float4 u1 = *(const float4*)(u + (size_t)node * 64 + d0 + 4);
        float4 o0, o1;
        o0.x = u0.x + a[0] * vi; o0.y = u0.y + a[1] * vi;
        o0.z = u0.z + a[2] * vi; o0.w = u0.w + a[3] * vi;
        o1.x = u1.x + a[4] * vi; o1.y = u1.y + a[5] * vi;
        o1.z = u1.z + a[6] * vi; o1.w = u1.w + a[7] * vi;
        if (RELU) {
            o0.x = fmaxf(o0.x, 0.f); o0.y = fmaxf(o0.y, 0.f);
            o0.z = fmaxf(o0.z, 0.f); o0.w = fmaxf(o0.w, 0.f);
            o1.x = fmaxf(o1.x, 0.f); o1.y = fmaxf(o1.y, 0.f);
            o1.z = fmaxf(o1.z, 0.f); o1.w = fmaxf(o1.w, 0.f);
        }
        *(float4*)(out + (size_t)node * 64 + d0)     = o0;
        *(float4*)(out + (size_t)node * 64 + d0 + 4) = o1;
    }
}

// T[M,64] (fp16) = A[M,K]@Wl ; U[M,64] (fp32) = A[M,K]@Wr + b
template<int K>
__global__ __launch_bounds__(256) void mm_dual(
    const float* __restrict__ A, const float* __restrict__ Wl,
    const float* __restrict__ Wr, const float* __restrict__ bias,
    __half* __restrict__ T, float* __restrict__ U, int M)
{
    __shared__ float As[64][68];
    __shared__ float Wls[64 * 64];
    __shared__ float Wrs[64 * 64];
    const int tid  = threadIdx.x;
    const int row0 = blockIdx.x * 64;
    const int tx = tid & 15, ty = tid >> 4;
    float accT[4][4] = {{0.f}}, accU[4][4] = {{0.f}};

    for (int kc = 0; kc < K; kc += 64) {
        for (int i = tid * 4; i < 64 * 64; i += 1024) {
            int r = i >> 6, c = i & 63;
            int gr = row0 + r;
            float4 v = make_float4(0.f, 0.f, 0.f, 0.f);
            if (gr < M) v = *(const float4*)&A[(size_t)gr * K + kc + c];
            *(float4*)&As[r][c] = v;
        }
        for (int i = tid * 4; i < 64 * 64; i += 1024) {
            *(float4*)&Wls[i] = *(const float4*)&Wl[kc * 64 + i];
            *(float4*)&Wrs[i] = *(const float4*)&Wr[kc * 64 + i];
        }
        __syncthreads();
        #pragma unroll 4
        for (int kk = 0; kk < 64; ++kk) {
            float a[4];
            #pragma unroll
            for (int r = 0; r < 4; ++r) a[r] = As[ty * 4 + r][kk];
            float bl[4], br[4];
            #pragma unroll
            for (int c = 0; c < 4; ++c) {
                bl[c] = Wls[kk * 64 + tx * 4 + c];
                br[c] = Wrs[kk * 64 + tx * 4 + c];
            }
            #pragma unroll
            for (int r = 0; r < 4; ++r)
                #pragma unroll
                for (int c = 0; c < 4; ++c) {
                    accT[r][c] += a[r] * bl[c];
                    accU[r][c] += a[r] * br[c];
                }
        }
        __syncthreads();
    }

    const float4 bv = *(const float4*)&bias[tx * 4];
    #pragma unroll
    for (int r = 0; r < 4; ++r) {
        int gr = row0 + ty * 4 + r;
        if (gr >= M) continue;
        union { int2 v; __half2 h[2]; } up;
        up.h[0] = __floats2half2_rn(accT[r][0], accT[r][1]);
        up.h[1] = __floats2half2_rn(accT[r][2], accT[r][3]);
        *(int2*)&T[(size_t)gr * 64 + tx * 4] = up.v;
        *(float4*)&U[(size_t)gr * 64 + tx * 4] =
            make_float4(accU[r][0] + bv.x, accU[r][1] + bv.y,
                        accU[r][2] + bv.z, accU[r][3] + bv.w);
    }
}

// final linear: C[M,32] = A[M,64]@W + b
__global__ __launch_bounds__(256) void mm_lin(
    const float* __restrict__ A, const float* __restrict__ W,
    const float* __restrict__ bias, float* __restrict__ C, int M)
{
    __shared__ float As[64][68];
    __shared__ float Ws[64 * 32];
    const int tid  = threadIdx.x;
    const int row0 = blockIdx.x * 64;

    for (int i = tid * 4; i < 64 * 32; i += 1024) {
        *(float4*)&Ws[i] = *(const float4*)&W[i];
    }
    for (int i = tid * 4; i < 64 * 64; i += 1024) {
        int r = i >> 6, c = i & 63;
        int gr = row0 + r;
        float4 v = make_float4(0.f, 0.f, 0.f, 0.f);
        if (gr < M) v = *(const float4*)&A[(size_t)gr * 64 + c];
        *(float4*)&As[r][c] = v;
    }
    __syncthreads();

    const int tx = tid & 15, ty = tid >> 4;
    float acc[4][2] = {{0.f}};
    #pragma unroll 4
    for (int kk = 0; kk < 64; ++kk) {
        float a[4];
        #pragma unroll
        for (int r = 0; r < 4; ++r) a[r] = As[ty * 4 + r][kk];
        float b0 = Ws[kk * 32 + tx * 2];
        float b1 = Ws[kk * 32 + tx * 2 + 1];
        #pragma unroll
        for (int r = 0; r < 4; ++r) {
            acc[r][0] += a[r] * b0;
            acc[r][1] += a[r] * b1;
        }
    }
    #pragma unroll
    for (int r = 0; r < 4; ++r) {
        int gr = row0 + ty * 4 + r;
        if (gr >= M) continue;
        float2 o = make_float2(acc[r][0] + bias[tx * 2],
                               acc[r][1] + bias[tx * 2 + 1]);
        *(float2*)&C[(size_t)gr * 32 + tx * 2] = o;
    }
}

extern "C" void kernel_launch(void* const* d_in, const int* in_sizes, int n_in,
                              void* d_out, int out_size, void* d_ws, size_t ws_size,
                              hipStream_t stream) {
    const float* x     = (const float*)d_in[0];
    const int*   ei    = (const int*)  d_in[1];
    const float* W1a_l = (const float*)d_in[2];
    const float* b1a   = (const float*)d_in[3];
    const float* W1a_r = (const float*)d_in[4];
    const float* W1b_l = (const float*)d_in[5];
    const float* b1b   = (const float*)d_in[6];
    const float* W1b_r = (const float*)d_in[7];
    const float* W2a_l = (const float*)d_in[8];
    const float* b2a   = (const float*)d_in[9];
    const float* W2a_r = (const float*)d_in[10];
    const float* W2b_l = (const float*)d_in[11];
    const float* b2b   = (const float*)d_in[12];
    const float* W2b_r = (const float*)d_in[13];
    const float* Wlin  = (const float*)d_in[14];
    const float* blin  = (const float*)d_in[15];

    const int N = in_sizes[0] / 128;
    const int E = in_sizes[1] / 2;
    const int nps = (N + NSLICE - 1) / NSLICE;     // nodes per slice
    const int nsb = (N + SCAN_NPB - 1) / SCAN_NPB; // scan blocks (25 @ N=50k)

    size_t o = 0;
    auto take = [&](size_t bytes) -> void* {
        void* p = (char*)d_ws + o;
        o += (bytes + 255) & ~(size_t)255;
        return p;
    };
    int*            ctr     = (int*)   take((size_t)NSLICE * 4);  // memset w/ cnt
    int*            cnt     = (int*)   take((size_t)N * 4);
    int*            row_ptr = (int*)   take((size_t)(N + 1) * 4);
    int*            cursor  = (int*)   take((size_t)N * 4);
    float*          inv     = (float*) take((size_t)N * 4);
    int*            partial = (int*)   take((size_t)64 * 4);
    unsigned short* e16     = (unsigned short*)take((size_t)E * 2 * 2);
    unsigned short* adj     = (unsigned short*)take((size_t)E * 2);
    __half*         t       = (__half*)take((size_t)N * 64 * 2);
    float*          u       = (float*) take((size_t)N * 64 * 4);
    float*          hA      = (float*) take((size_t)N * 64 * 4);
    float*          hB      = (float*) take((size_t)N * 64 * 4);
    (void)ws_size; (void)n_in; (void)out_size;

    const unsigned short* src16 = e16;
    const unsigned short* dst16 = e16 + E;

    const int mb = (N + 63) / 64;                 // mm blocks
    const int gb = (N * 64 + 255) / 256;          // gather blocks (wave/node)

    // ---- build CSR ----
    const int fill_chunks = 256;                  // chunks per slice
    hipMemsetAsync(ctr, 0, 256 + (size_t)N * 4, stream);  // ctr + cnt
    pack_count<<<(2 * E / 4 + 255) / 256, 256, 0, stream>>>(ei, e16, cnt, E);
    scan_partial<<<nsb, 256, 0, stream>>>(cnt, partial, N);
    scan_partial_scan<<<1, 64, 0, stream>>>(partial, nsb);
    scan_final<<<nsb, 256, 0, stream>>>(cnt, partial, row_ptr, cursor, inv, N);
    fill_xcd<<<2048, 256, 0, stream>>>(
        src16, dst16, cursor, adj, ctr, E, N, nps, fill_chunks);

    // ---- layer 1a: x[*,128] -> hA, relu ----
    mm_dual<128><<<mb, 256, 0, stream>>>(x, W1a_l, W1a_r, b1a, t, u, N);
    gather_fused<true><<<gb, 256, 0, stream>>>(t, adj, row_ptr, inv, u, hA, N);
    // ---- layer 1b: hA -> hB, relu ----
    mm_dual<64><<<mb, 256, 0, stream>>>(hA, W1b_l, W1b_r, b1b, t, u, N);
    gather_fused<true><<<gb, 256, 0, stream>>>(t, adj, row_ptr, inv, u, hB, N);
    // ---- layer 2a: hB -> hA, relu ----
    mm_dual<64><<<mb, 256, 0, stream>>>(hB, W2a_l, W2a_r, b2a, t, u, N);
    gather_fused<true><<<gb, 256, 0, stream>>>(t, adj, row_ptr, inv, u, hA, N);
    // ---- layer 2b: hA -> hB, no relu ----
    mm_dual<64><<<mb, 256, 0, stream>>>(hA, W2b_l, W2b_r, b2b, t, u, N);
    gather_fused<false><<<gb, 256, 0, stream>>>(t, adj, row_ptr, inv, u, hB, N);
    // ---- final linear ----
    mm_lin<<<mb, 256, 0, stream>>>(hB, Wlin, blin, (float*)d_out, N);
}

// Round 11
// 290.455 us; speedup vs baseline: 2.0016x; 2.0016x over previous
//
#include <hip/hip_runtime.h>
#include <hip/hip_fp16.h>

// ---------------------------------------------------------------------------
// GNNEncoder: 4x SAGEConv + linear. R10:
//  ATOMIC-FREE CSR BUILD (global atomics write ~32B through the memory-side
//  coherence point: R0 410M atomics = 1.6GB WRITE exactly; R7/8/9 1.6M = 51MB
//  invariant under slicing/XCD-binding/NT). All rank/count atomics now in LDS.
//   A hist_pack:    pack (src<<16|dst)->pe, LDS hist per 512-node slice,
//                   counts[slice][block] (391 chunks x 4096 edges, 98 slices)
//   B scan_cols:    per-slice exclusive scan over blocks -> offs, stotal
//   B2 scan_slices: exclusive scan of stotal -> sbase (== row_ptr base)
//   C bucket_scatter: re-read pe, LDS-rank, deterministic bucket write
//   D csr_fill:     per-slice block: LDS node-count + LDS scan -> row_ptr,
//                   inv, LDS-cursor scatter -> adj. Zero global atomics.
//  - gather: wave/node, 8 nbr-groups x 8 dim-lanes, fp16 t, fused self+relu.
//  - mm_dual: t(fp16) = h@Wl, u = h@Wr + b in one pass.
// ---------------------------------------------------------------------------

#define CHUNK 4096          // edges per partition block
#define SLICE_W 512         // nodes per slice (dst>>9)
#define MAXS 128            // max slices (N <= 65536)

// ---- A: pack + per-(slice,block) histogram (LDS atomics only) ----
__global__ __launch_bounds__(256) void hist_pack(
    const int* __restrict__ e32, unsigned* __restrict__ pe,
    int* __restrict__ counts, int E, int S, int Bpad)
{
    __shared__ int h[MAXS];
    const int tid = threadIdx.x, b = blockIdx.x;
    for (int i = tid; i < S; i += 256) h[i] = 0;
    __syncthreads();
    const int lo = b * CHUNK, hi = min(lo + CHUNK, E);
    for (int e = lo + tid; e < hi; e += 256) {
        const int s = e32[e];
        const int d = e32[E + e];
        pe[e] = ((unsigned)s << 16) | (unsigned)d;
        atomicAdd(&h[d >> 9], 1);
    }
    __syncthreads();
    for (int i = tid; i < S; i += 256) counts[i * Bpad + b] = h[i];
}

// ---- B: per-slice exclusive scan over B blocks (B <= 512) ----
__global__ __launch_bounds__(512) void scan_cols(
    int* __restrict__ counts, int* __restrict__ stotal, int B, int Bpad)
{
    __shared__ int sc[512];
    const int s = blockIdx.x, tid = threadIdx.x;
    const int v = (tid < B) ? counts[s * Bpad + tid] : 0;
    sc[tid] = v;
    __syncthreads();
    for (int off = 1; off < 512; off <<= 1) {
        const int a = (tid >= off) ? sc[tid - off] : 0;
        __syncthreads();
        sc[tid] += a;
        __syncthreads();
    }
    if (tid < B) counts[s * Bpad + tid] = sc[tid] - v;   // exclusive
    if (tid == 0) stotal[s] = sc[511];
}

// ---- B2: exclusive scan of slice totals -> slice/bucket/row_ptr bases ----
__global__ __launch_bounds__(MAXS) void scan_slices(
    const int* __restrict__ stotal, int* __restrict__ sbase, int S)
{
    __shared__ int sc[MAXS];
    const int tid = threadIdx.x;
    const int v = (tid < S) ? stotal[tid] : 0;
    sc[tid] = v;
    __syncthreads();
    for (int off = 1; off < MAXS; off <<= 1) {
        const int a = (tid >= off) ? sc[tid - off] : 0;
        __syncthreads();
        sc[tid] += a;
        __syncthreads();
    }
    if (tid < S) sbase[tid] = sc[tid] - v;
}

// ---- C: scatter edges into slice buckets at deterministic positions ----
__global__ __launch_bounds__(256) void bucket_scatter(
    const unsigned* __restrict__ pe, const int* __restrict__ counts,
    const int* __restrict__ sbase, unsigned* __restrict__ bedge,
    int E, int S, int Bpad)
{
    __shared__ int h[MAXS];
    const int tid = threadIdx.x, b = blockIdx.x;
    for (int i = tid; i < S; i += 256) h[i] = 0;
    __syncthreads();
    const int lo = b * CHUNK, hi = min(lo + CHUNK, E);
    for (int e = lo + tid; e < hi; e += 256) {
        const unsigned v = pe[e];
        const int sl = (int)(v & 0xFFFFu) >> 9;
        const int r = atomicAdd(&h[sl], 1);               // LDS rank
        bedge[sbase[sl] + counts[sl * Bpad + b] + r] = v;
    }
}

// ---- D: per-slice CSR finalize: row_ptr, inv, adj (LDS cursors) ----
__global__ __launch_bounds__(256) void csr_fill(
    const unsigned* __restrict__ bedge, const int* __restrict__ stotal,
    const int* __restrict__ sbase, int* __restrict__ row_ptr,
    float* __restrict__ inv, unsigned short* __restrict__ adj, int N, int E)
{
    __shared__ int cnt[SLICE_W];
    __shared__ int sc[SLICE_W];
    const int s = blockIdx.x, tid = threadIdx.x;
    const int n = stotal[s], base = sbase[s];
    cnt[tid] = 0; cnt[tid + 256] = 0;
    __syncthreads();
    for (int i = tid; i < n; i += 256)
        atomicAdd(&cnt[bedge[base + i] & (SLICE_W - 1)], 1);
    __syncthreads();
    sc[tid] = cnt[tid]; sc[tid + 256] = cnt[tid + 256];
    __syncthreads();
    for (int off = 1; off < SLICE_W; off <<= 1) {
        const int a0 = (tid >= off) ? sc[tid - off] : 0;
        const int a1 = (tid + 256 >= off) ? sc[tid + 256 - off] : 0;
        __syncthreads();
        sc[tid] += a0; sc[tid + 256] += a1;
        __syncthreads();
    }
    #pragma unroll
    for (int k = 0; k < 2; ++k) {
        const int i = tid + k * 256;
        const int c = cnt[i];
        const int excl = sc[i] - c;
        const int node = (s << 9) + i;
        if (node < N) {
            row_ptr[node] = base + excl;
            inv[node] = 1.0f / (float)(c > 0 ? c : 1);
        }
        cnt[i] = excl;                     // becomes the cursor
    }
    __syncthreads();
    for (int i = tid; i < n; i += 256) {
        const unsigned v = bedge[base + i];
        const int p = atomicAdd(&cnt[v & (SLICE_W - 1)], 1);   // LDS cursor
        adj[base + p] = (unsigned short)(v >> 16);
    }
    if (s == 0 && tid == 0) row_ptr[N] = E;
}

// pull aggregation fused with self-term: out = (relu)(u + inv * sum_j t[adj_j])
// one wave per node: 8 neighbor-groups x 8 dim-lanes, half8 (16B) per lane.
template<bool RELU>
__global__ __launch_bounds__(256) void gather_fused(
    const __half* __restrict__ t, const unsigned short* __restrict__ adj,
    const int* __restrict__ row_ptr, const float* __restrict__ inv,
    const float* __restrict__ u, float* __restrict__ out, int N)
{
    const int node = (blockIdx.x * 256 + threadIdx.x) >> 6;
    const int lane = threadIdx.x & 63;
    const int grp  = lane >> 3;          // 0..7: neighbor slot in the octet
    const int d0   = (lane & 7) * 8;     // dim offset (8 dims per lane)
    if (node >= N) return;
    const int beg = row_ptr[node], end = row_ptr[node + 1];
    float a[8] = {0.f, 0.f, 0.f, 0.f, 0.f, 0.f, 0.f, 0.f};
    int j = beg + grp;
    for (; j + 8 < end; j += 16) {       // 2x unrolled: j and j+8
        const int n0 = adj[j], n1 = adj[j + 8];
        const float4 p0 = *(const float4*)(t + (size_t)n0 * 64 + d0);
        const float4 p1 = *(const float4*)(t + (size_t)n1 * 64 + d0);
        const __half2* h0 = (const __half2*)&p0;
        const __half2* h1 = (const __half2*)&p1;
        #pragma unroll
        for (int k = 0; k < 4; ++k) {
            float2 f0 = __half22float2(h0[k]);
            float2 f1 = __half22float2(h1[k]);
            a[2 * k]     += f0.x + f1.x;
            a[2 * k + 1] += f0.y + f1.y;
        }
    }
    if (j < end) {
        const float4 p0 = *(const float4*)(t + (size_t)adj[j] * 64 + d0);
        const __half2* h0 = (const __half2*)&p0;
        #pragma unroll
        for (int k = 0; k < 4; ++k) {
            float2 f0 = __half22float2(h0[k]);
            a[2 * k]     += f0.x;
            a[2 * k + 1] += f0.y;
        }
    }
    // reduce across the 8 groups (lane bits 3,4,5)
    #pragma unroll
    for (int k = 0; k < 8; ++k) {
        a[k] += __shfl_xor(a[k], 8);
        a[k] += __shfl_xor(a[k], 16);
        a[k] += __shfl_xor(a[k], 32);
    }
    if (grp == 0) {
        const float vi = inv[node];
        const float4 u0 = *(const float4*)(u + (size_t)node * 64 + d0);
        const float4 u1 = *(const float4*)(u + (size_t)node * 64 + d0 + 4);
        float4 o0, o1;
        o0.x = u0.x + a[0] * vi; o0.y = u0.y + a[1] * vi;
        o0.z = u0.z + a[2] * vi; o0.w = u0.w + a[3] * vi;
        o1.x = u1.x + a[4] * vi; o1.y = u1.y + a[5] * vi;
        o1.z = u1.z + a[6] * vi; o1.w = u1.w + a[7] * vi;
        if (RELU) {
            o0.x = fmaxf(o0.x, 0.f); o0.y = fmaxf(o0.y, 0.f);
            o0.z = fmaxf(o0.z, 0.f); o0.w = fmaxf(o0.w, 0.f);
            o1.x = fmaxf(o1.x, 0.f); o1.y = fmaxf(o1.y, 0.f);
            o1.z = fmaxf(o1.z, 0.f); o1.w = fmaxf(o1.w, 0.f);
        }
        *(float4*)(out + (size_t)node * 64 + d0)     = o0;
        *(float4*)(out + (size_t)node * 64 + d0 + 4) = o1;
    }
}

// T[M,64] (fp16) = A[M,K]@Wl ; U[M,64] (fp32) = A[M,K]@Wr + b
template<int K>
__global__ __launch_bounds__(256) void mm_dual(
    const float* __restrict__ A, const float* __restrict__ Wl,
    const float* __restrict__ Wr, const float* __restrict__ bias,
    __half* __restrict__ T, float* __restrict__ U, int M)
{
    __shared__ float As[64][68];
    __shared__ float Wls[64 * 64];
    __shared__ float Wrs[64 * 64];
    const int tid  = threadIdx.x;
    const int row0 = blockIdx.x * 64;
    const int tx = tid & 15, ty = tid >> 4;
    float accT[4][4] = {{0.f}}, accU[4][4] = {{0.f}};

    for (int kc = 0; kc < K; kc += 64) {
        for (int i = tid * 4; i < 64 * 64; i += 1024) {
            int r = i >> 6, c = i & 63;
            int gr = row0 + r;
            float4 v = make_float4(0.f, 0.f, 0.f, 0.f);
            if (gr < M) v = *(const float4*)&A[(size_t)gr * K + kc + c];
            *(float4*)&As[r][c] = v;
        }
        for (int i = tid * 4; i < 64 * 64; i += 1024) {
            *(float4*)&Wls[i] = *(const float4*)&Wl[kc * 64 + i];
            *(float4*)&Wrs[i] = *(const float4*)&Wr[kc * 64 + i];
        }
        __syncthreads();
        #pragma unroll 4
        for (int kk = 0; kk < 64; ++kk) {
            float a[4];
            #pragma unroll
            for (int r = 0; r < 4; ++r) a[r] = As[ty * 4 + r][kk];
            float bl[4], br[4];
            #pragma unroll
            for (int c = 0; c < 4; ++c) {
                bl[c] = Wls[kk * 64 + tx * 4 + c];
                br[c] = Wrs[kk * 64 + tx * 4 + c];
            }
            #pragma unroll
            for (int r = 0; r < 4; ++r)
                #pragma unroll
                for (int c = 0; c < 4; ++c) {
                    accT[r][c] += a[r] * bl[c];
                    accU[r][c] += a[r] * br[c];
                }
        }
        __syncthreads();
    }

    const float4 bv = *(const float4*)&bias[tx * 4];
    #pragma unroll
    for (int r = 0; r < 4; ++r) {
        int gr = row0 + ty * 4 + r;
        if (gr >= M) continue;
        union { int2 v; __half2 h[2]; } up;
        up.h[0] = __floats2half2_rn(accT[r][0], accT[r][1]);
        up.h[1] = __floats2half2_rn(accT[r][2], accT[r][3]);
        *(int2*)&T[(size_t)gr * 64 + tx * 4] = up.v;
        *(float4*)&U[(size_t)gr * 64 + tx * 4] =
            make_float4(accU[r][0] + bv.x, accU[r][1] + bv.y,
                        accU[r][2] + bv.z, accU[r][3] + bv.w);
    }
}

// final linear: C[M,32] = A[M,64]@W + b
__global__ __launch_bounds__(256) void mm_lin(
    const float* __restrict__ A, const float* __restrict__ W,
    const float* __restrict__ bias, float* __restrict__ C, int M)
{
    __shared__ float As[64][68];
    __shared__ float Ws[64 * 32];
    const int tid  = threadIdx.x;
    const int row0 = blockIdx.x * 64;

    for (int i = tid * 4; i < 64 * 32; i += 1024) {
        *(float4*)&Ws[i] = *(const float4*)&W[i];
    }
    for (int i = tid * 4; i < 64 * 64; i += 1024) {
        int r = i >> 6, c = i & 63;
        int gr = row0 + r;
        float4 v = make_float4(0.f, 0.f, 0.f, 0.f);
        if (gr < M) v = *(const float4*)&A[(size_t)gr * 64 + c];
        *(float4*)&As[r][c] = v;
    }
    __syncthreads();

    const int tx = tid & 15, ty = tid >> 4;
    float acc[4][2] = {{0.f}};
    #pragma unroll 4
    for (int kk = 0; kk < 64; ++kk) {
        float a[4];
        #pragma unroll
        for (int r = 0; r < 4; ++r) a[r] = As[ty * 4 + r][kk];
        float b0 = Ws[kk * 32 + tx * 2];
        float b1 = Ws[kk * 32 + tx * 2 + 1];
        #pragma unroll
        for (int r = 0; r < 4; ++r) {
            acc[r][0] += a[r] * b0;
            acc[r][1] += a[r] * b1;
        }
    }
    #pragma unroll
    for (int r = 0; r < 4; ++r) {
        int gr = row0 + ty * 4 + r;
        if (gr >= M) continue;
        float2 o = make_float2(acc[r][0] + bias[tx * 2],
                               acc[r][1] + bias[tx * 2 + 1]);
        *(float2*)&C[(size_t)gr * 32 + tx * 2] = o;
    }
}

extern "C" void kernel_launch(void* const* d_in, const int* in_sizes, int n_in,
                              void* d_out, int out_size, void* d_ws, size_t ws_size,
                              hipStream_t stream) {
    const float* x     = (const float*)d_in[0];
    const int*   ei    = (const int*)  d_in[1];
    const float* W1a_l = (const float*)d_in[2];
    const float* b1a   = (const float*)d_in[3];
    const float* W1a_r = (const float*)d_in[4];
    const float* W1b_l = (const float*)d_in[5];
    const float* b1b   = (const float*)d_in[6];
    const float* W1b_r = (const float*)d_in[7];
    const float* W2a_l = (const float*)d_in[8];
    const float* b2a   = (const float*)d_in[9];
    const float* W2a_r = (const float*)d_in[10];
    const float* W2b_l = (const float*)d_in[11];
    const float* b2b   = (const float*)d_in[12];
    const float* W2b_r = (const float*)d_in[13];
    const float* Wlin  = (const float*)d_in[14];
    const float* blin  = (const float*)d_in[15];

    const int N = in_sizes[0] / 128;
    const int E = in_sizes[1] / 2;
    const int S = (N + SLICE_W - 1) / SLICE_W;      // 98 slices @ N=50k
    const int B = (E + CHUNK - 1) / CHUNK;          // 391 chunks @ E=1.6M
    const int Bpad = (B + 15) & ~15;                // 400

    size_t o = 0;
    auto take = [&](size_t bytes) -> void* {
        void* p = (char*)d_ws + o;
        o += (bytes + 255) & ~(size_t)255;
        return p;
    };
    unsigned*       pe      = (unsigned*)take((size_t)E * 4);
    unsigned*       bedge   = (unsigned*)take((size_t)E * 4);
    int*            counts  = (int*)   take((size_t)S * Bpad * 4);
    int*            stotal  = (int*)   take((size_t)S * 4);
    int*            sbase   = (int*)   take((size_t)S * 4);
    int*            row_ptr = (int*)   take((size_t)(N + 1) * 4);
    float*          inv     = (float*) take((size_t)N * 4);
    unsigned short* adj     = (unsigned short*)take((size_t)E * 2);
    __half*         t       = (__half*)take((size_t)N * 64 * 2);
    float*          u       = (float*) take((size_t)N * 64 * 4);
    float*          hA      = (float*) take((size_t)N * 64 * 4);
    float*          hB      = (float*) take((size_t)N * 64 * 4);
    (void)ws_size; (void)n_in; (void)out_size;

    const int mb = (N + 63) / 64;                 // mm blocks
    const int gb = (N * 64 + 255) / 256;          // gather blocks (wave/node)

    // ---- build CSR: zero global atomics ----
    hist_pack<<<B, 256, 0, stream>>>(ei, pe, counts, E, S, Bpad);
    scan_cols<<<S, 512, 0, stream>>>(counts, stotal, B, Bpad);
    scan_slices<<<1, MAXS, 0, stream>>>(stotal, sbase, S);
    bucket_scatter<<<B, 256, 0, stream>>>(pe, counts, sbase, bedge, E, S, Bpad);
    csr_fill<<<S, 256, 0, stream>>>(bedge, stotal, sbase, row_ptr, inv, adj, N, E);

    // ---- layer 1a: x[*,128] -> hA, relu ----
    mm_dual<128><<<mb, 256, 0, stream>>>(x, W1a_l, W1a_r, b1a, t, u, N);
    gather_fused<true><<<gb, 256, 0, stream>>>(t, adj, row_ptr, inv, u, hA, N);
    // ---- layer 1b: hA -> hB, relu ----
    mm_dual<64><<<mb, 256, 0, stream>>>(hA, W1b_l, W1b_r, b1b, t, u, N);
    gather_fused<true><<<gb, 256, 0, stream>>>(t, adj, row_ptr, inv, u, hB, N);
    // ---- layer 2a: hB -> hA, relu ----
    mm_dual<64><<<mb, 256, 0, stream>>>(hB, W2a_l, W2a_r, b2a, t, u, N);
    gather_fused<true><<<gb, 256, 0, stream>>>(t, adj, row_ptr, inv, u, hA, N);
    // ---- layer 2b: hA -> hB, no relu ----
    mm_dual<64><<<mb, 256, 0, stream>>>(hA, W2b_l, W2b_r, b2b, t, u, N);
    gather_fused<false><<<gb, 256, 0, stream>>>(t, adj, row_ptr, inv, u, hB, N);
    // ---- final linear ----
    mm_lin<<<mb, 256, 0, stream>>>(hB, Wlin, blin, (float*)d_out, N);
}

// Round 12
// 270.099 us; speedup vs baseline: 2.1525x; 1.0754x over previous
//
#include <hip/hip_runtime.h>
#include <hip/hip_fp16.h>

// ---------------------------------------------------------------------------
// GNNEncoder: 4x SAGEConv + linear. R11 (on R10's atomic-free CSR build):
//  - csr_fill: 1024 threads/block (was 256; 98-block kernel ran at 3.4%
//    occupancy, 40us). Count/scatter loops 64 -> 16 iters.
//  - u stored fp16: mm_dual packs (half2 x2), gather reads 8 halves in ONE
//    16B load. u traffic halved both sides. t fp16 unchanged.
//  - CSR pipeline (hist_pack -> scan_cols -> scan_slices -> bucket_scatter
//    -> csr_fill): zero global atomics (32B-writethrough-per-atomic lesson).
// ---------------------------------------------------------------------------

#define CHUNK 4096          // edges per partition block
#define SLICE_W 512         // nodes per slice (dst>>9)
#define MAXS 128            // max slices (N <= 65536)

// ---- A: pack + per-(slice,block) histogram (LDS atomics only) ----
__global__ __launch_bounds__(256) void hist_pack(
    const int* __restrict__ e32, unsigned* __restrict__ pe,
    int* __restrict__ counts, int E, int S, int Bpad)
{
    __shared__ int h[MAXS];
    const int tid = threadIdx.x, b = blockIdx.x;
    for (int i = tid; i < S; i += 256) h[i] = 0;
    __syncthreads();
    const int lo = b * CHUNK, hi = min(lo + CHUNK, E);
    for (int e = lo + tid; e < hi; e += 256) {
        const int s = e32[e];
        const int d = e32[E + e];
        pe[e] = ((unsigned)s << 16) | (unsigned)d;
        atomicAdd(&h[d >> 9], 1);
    }
    __syncthreads();
    for (int i = tid; i < S; i += 256) counts[i * Bpad + b] = h[i];
}

// ---- B: per-slice exclusive scan over B blocks (B <= 512) ----
__global__ __launch_bounds__(512) void scan_cols(
    int* __restrict__ counts, int* __restrict__ stotal, int B, int Bpad)
{
    __shared__ int sc[512];
    const int s = blockIdx.x, tid = threadIdx.x;
    const int v = (tid < B) ? counts[s * Bpad + tid] : 0;
    sc[tid] = v;
    __syncthreads();
    for (int off = 1; off < 512; off <<= 1) {
        const int a = (tid >= off) ? sc[tid - off] : 0;
        __syncthreads();
        sc[tid] += a;
        __syncthreads();
    }
    if (tid < B) counts[s * Bpad + tid] = sc[tid] - v;   // exclusive
    if (tid == 0) stotal[s] = sc[511];
}

// ---- B2: exclusive scan of slice totals -> slice/bucket/row_ptr bases ----
__global__ __launch_bounds__(MAXS) void scan_slices(
    const int* __restrict__ stotal, int* __restrict__ sbase, int S)
{
    __shared__ int sc[MAXS];
    const int tid = threadIdx.x;
    const int v = (tid < S) ? stotal[tid] : 0;
    sc[tid] = v;
    __syncthreads();
    for (int off = 1; off < MAXS; off <<= 1) {
        const int a = (tid >= off) ? sc[tid - off] : 0;
        __syncthreads();
        sc[tid] += a;
        __syncthreads();
    }
    if (tid < S) sbase[tid] = sc[tid] - v;
}

// ---- C: scatter edges into slice buckets at deterministic positions ----
__global__ __launch_bounds__(256) void bucket_scatter(
    const unsigned* __restrict__ pe, const int* __restrict__ counts,
    const int* __restrict__ sbase, unsigned* __restrict__ bedge,
    int E, int S, int Bpad)
{
    __shared__ int h[MAXS];
    const int tid = threadIdx.x, b = blockIdx.x;
    for (int i = tid; i < S; i += 256) h[i] = 0;
    __syncthreads();
    const int lo = b * CHUNK, hi = min(lo + CHUNK, E);
    for (int e = lo + tid; e < hi; e += 256) {
        const unsigned v = pe[e];
        const int sl = (int)(v & 0xFFFFu) >> 9;
        const int r = atomicAdd(&h[sl], 1);               // LDS rank
        bedge[sbase[sl] + counts[sl * Bpad + b] + r] = v;
    }
}

// ---- D: per-slice CSR finalize: row_ptr, inv, adj (LDS cursors) ----
__global__ __launch_bounds__(1024) void csr_fill(
    const unsigned* __restrict__ bedge, const int* __restrict__ stotal,
    const int* __restrict__ sbase, int* __restrict__ row_ptr,
    float* __restrict__ inv, unsigned short* __restrict__ adj, int N, int E)
{
    __shared__ int cnt[SLICE_W];
    __shared__ int sc[SLICE_W];
    const int s = blockIdx.x, tid = threadIdx.x;
    const int n = stotal[s], base = sbase[s];
    if (tid < SLICE_W) cnt[tid] = 0;
    __syncthreads();
    for (int i = tid; i < n; i += 1024)
        atomicAdd(&cnt[bedge[base + i] & (SLICE_W - 1)], 1);
    __syncthreads();
    if (tid < SLICE_W) sc[tid] = cnt[tid];
    __syncthreads();
    for (int off = 1; off < SLICE_W; off <<= 1) {
        int a = 0;
        if (tid < SLICE_W && tid >= off) a = sc[tid - off];
        __syncthreads();
        if (tid < SLICE_W) sc[tid] += a;
        __syncthreads();
    }
    if (tid < SLICE_W) {
        const int c = cnt[tid];
        const int excl = sc[tid] - c;
        const int node = (s << 9) + tid;
        if (node < N) {
            row_ptr[node] = base + excl;
            inv[node] = 1.0f / (float)(c > 0 ? c : 1);
        }
        cnt[tid] = excl;                   // becomes the cursor
    }
    __syncthreads();
    for (int i = tid; i < n; i += 1024) {
        const unsigned v = bedge[base + i];
        const int p = atomicAdd(&cnt[v & (SLICE_W - 1)], 1);   // LDS cursor
        adj[base + p] = (unsigned short)(v >> 16);
    }
    if (s == 0 && tid == 0) row_ptr[N] = E;
}

// pull aggregation fused with self-term: out = (relu)(u + inv * sum_j t[adj_j])
// one wave per node: 8 neighbor-groups x 8 dim-lanes, half8 (16B) per lane.
// u is fp16: all 8 dims/lane arrive in a single 16B load.
template<bool RELU>
__global__ __launch_bounds__(256) void gather_fused(
    const __half* __restrict__ t, const unsigned short* __restrict__ adj,
    const int* __restrict__ row_ptr, const float* __restrict__ inv,
    const __half* __restrict__ u, float* __restrict__ out, int N)
{
    const int node = (blockIdx.x * 256 + threadIdx.x) >> 6;
    const int lane = threadIdx.x & 63;
    const int grp  = lane >> 3;          // 0..7: neighbor slot in the octet
    const int d0   = (lane & 7) * 8;     // dim offset (8 dims per lane)
    if (node >= N) return;
    const int beg = row_ptr[node], end = row_ptr[node + 1];
    float a[8] = {0.f, 0.f, 0.f, 0.f, 0.f, 0.f, 0.f, 0.f};
    int j = beg + grp;
    for (; j + 8 < end; j += 16) {       // 2x unrolled: j and j+8
        const int n0 = adj[j], n1 = adj[j + 8];
        const float4 p0 = *(const float4*)(t + (size_t)n0 * 64 + d0);
        const float4 p1 = *(const float4*)(t + (size_t)n1 * 64 + d0);
        const __half2* h0 = (const __half2*)&p0;
        const __half2* h1 = (const __half2*)&p1;
        #pragma unroll
        for (int k = 0; k < 4; ++k) {
            float2 f0 = __half22float2(h0[k]);
            float2 f1 = __half22float2(h1[k]);
            a[2 * k]     += f0.x + f1.x;
            a[2 * k + 1] += f0.y + f1.y;
        }
    }
    if (j < end) {
        const float4 p0 = *(const float4*)(t + (size_t)adj[j] * 64 + d0);
        const __half2* h0 = (const __half2*)&p0;
        #pragma unroll
        for (int k = 0; k < 4; ++k) {
            float2 f0 = __half22float2(h0[k]);
            a[2 * k]     += f0.x;
            a[2 * k + 1] += f0.y;
        }
    }
    // reduce across the 8 groups (lane bits 3,4,5)
    #pragma unroll
    for (int k = 0; k < 8; ++k) {
        a[k] += __shfl_xor(a[k], 8);
        a[k] += __shfl_xor(a[k], 16);
        a[k] += __shfl_xor(a[k], 32);
    }
    if (grp == 0) {
        const float vi = inv[node];
        const float4 uv = *(const float4*)(u + (size_t)node * 64 + d0);
        const __half2* uh = (const __half2*)&uv;
        float4 o0, o1;
        {
            float2 g0 = __half22float2(uh[0]);
            float2 g1 = __half22float2(uh[1]);
            float2 g2 = __half22float2(uh[2]);
            float2 g3 = __half22float2(uh[3]);
            o0.x = g0.x + a[0] * vi; o0.y = g0.y + a[1] * vi;
            o0.z = g1.x + a[2] * vi; o0.w = g1.y + a[3] * vi;
            o1.x = g2.x + a[4] * vi; o1.y = g2.y + a[5] * vi;
            o1.z = g3.x + a[6] * vi; o1.w = g3.y + a[7] * vi;
        }
        if (RELU) {
            o0.x = fmaxf(o0.x, 0.f); o0.y = fmaxf(o0.y, 0.f);
            o0.z = fmaxf(o0.z, 0.f); o0.w = fmaxf(o0.w, 0.f);
            o1.x = fmaxf(o1.x, 0.f); o1.y = fmaxf(o1.y, 0.f);
            o1.z = fmaxf(o1.z, 0.f); o1.w = fmaxf(o1.w, 0.f);
        }
        *(float4*)(out + (size_t)node * 64 + d0)     = o0;
        *(float4*)(out + (size_t)node * 64 + d0 + 4) = o1;
    }
}

// T[M,64] (fp16) = A[M,K]@Wl ; U[M,64] (fp16) = A[M,K]@Wr + b
template<int K>
__global__ __launch_bounds__(256) void mm_dual(
    const float* __restrict__ A, const float* __restrict__ Wl,
    const float* __restrict__ Wr, const float* __restrict__ bias,
    __half* __restrict__ T, __half* __restrict__ U, int M)
{
    __shared__ float As[64][68];
    __shared__ float Wls[64 * 64];
    __shared__ float Wrs[64 * 64];
    const int tid  = threadIdx.x;
    const int row0 = blockIdx.x * 64;
    const int tx = tid & 15, ty = tid >> 4;
    float accT[4][4] = {{0.f}}, accU[4][4] = {{0.f}};

    for (int kc = 0; kc < K; kc += 64) {
        for (int i = tid * 4; i < 64 * 64; i += 1024) {
            int r = i >> 6, c = i & 63;
            int gr = row0 + r;
            float4 v = make_float4(0.f, 0.f, 0.f, 0.f);
            if (gr < M) v = *(const float4*)&A[(size_t)gr * K + kc + c];
            *(float4*)&As[r][c] = v;
        }
        for (int i = tid * 4; i < 64 * 64; i += 1024) {
            *(float4*)&Wls[i] = *(const float4*)&Wl[kc * 64 + i];
            *(float4*)&Wrs[i] = *(const float4*)&Wr[kc * 64 + i];
        }
        __syncthreads();
        #pragma unroll 4
        for (int kk = 0; kk < 64; ++kk) {
            float a[4];
            #pragma unroll
            for (int r = 0; r < 4; ++r) a[r] = As[ty * 4 + r][kk];
            float bl[4], br[4];
            #pragma unroll
            for (int c = 0; c < 4; ++c) {
                bl[c] = Wls[kk * 64 + tx * 4 + c];
                br[c] = Wrs[kk * 64 + tx * 4 + c];
            }
            #pragma unroll
            for (int r = 0; r < 4; ++r)
                #pragma unroll
                for (int c = 0; c < 4; ++c) {
                    accT[r][c] += a[r] * bl[c];
                    accU[r][c] += a[r] * br[c];
                }
        }
        __syncthreads();
    }

    const float4 bv = *(const float4*)&bias[tx * 4];
    #pragma unroll
    for (int r = 0; r < 4; ++r) {
        int gr = row0 + ty * 4 + r;
        if (gr >= M) continue;
        union { int2 v; __half2 h[2]; } tp;
        tp.h[0] = __floats2half2_rn(accT[r][0], accT[r][1]);
        tp.h[1] = __floats2half2_rn(accT[r][2], accT[r][3]);
        *(int2*)&T[(size_t)gr * 64 + tx * 4] = tp.v;
        union { int2 v; __half2 h[2]; } up;
        up.h[0] = __floats2half2_rn(accU[r][0] + bv.x, accU[r][1] + bv.y);
        up.h[1] = __floats2half2_rn(accU[r][2] + bv.z, accU[r][3] + bv.w);
        *(int2*)&U[(size_t)gr * 64 + tx * 4] = up.v;
    }
}

// final linear: C[M,32] = A[M,64]@W + b
__global__ __launch_bounds__(256) void mm_lin(
    const float* __restrict__ A, const float* __restrict__ W,
    const float* __restrict__ bias, float* __restrict__ C, int M)
{
    __shared__ float As[64][68];
    __shared__ float Ws[64 * 32];
    const int tid  = threadIdx.x;
    const int row0 = blockIdx.x * 64;

    for (int i = tid * 4; i < 64 * 32; i += 1024) {
        *(float4*)&Ws[i] = *(const float4*)&W[i];
    }
    for (int i = tid * 4; i < 64 * 64; i += 1024) {
        int r = i >> 6, c = i & 63;
        int gr = row0 + r;
        float4 v = make_float4(0.f, 0.f, 0.f, 0.f);
        if (gr < M) v = *(const float4*)&A[(size_t)gr * 64 + c];
        *(float4*)&As[r][c] = v;
    }
    __syncthreads();

    const int tx = tid & 15, ty = tid >> 4;
    float acc[4][2] = {{0.f}};
    #pragma unroll 4
    for (int kk = 0; kk < 64; ++kk) {
        float a[4];
        #pragma unroll
        for (int r = 0; r < 4; ++r) a[r] = As[ty * 4 + r][kk];
        float b0 = Ws[kk * 32 + tx * 2];
        float b1 = Ws[kk * 32 + tx * 2 + 1];
        #pragma unroll
        for (int r = 0; r < 4; ++r) {
            acc[r][0] += a[r] * b0;
            acc[r][1] += a[r] * b1;
        }
    }
    #pragma unroll
    for (int r = 0; r < 4; ++r) {
        int gr = row0 + ty * 4 + r;
        if (gr >= M) continue;
        float2 o = make_float2(acc[r][0] + bias[tx * 2],
                               acc[r][1] + bias[tx * 2 + 1]);
        *(float2*)&C[(size_t)gr * 32 + tx * 2] = o;
    }
}

extern "C" void kernel_launch(void* const* d_in, const int* in_sizes, int n_in,
                              void* d_out, int out_size, void* d_ws, size_t ws_size,
                              hipStream_t stream) {
    const float* x     = (const float*)d_in[0];
    const int*   ei    = (const int*)  d_in[1];
    const float* W1a_l = (const float*)d_in[2];
    const float* b1a   = (const float*)d_in[3];
    const float* W1a_r = (const float*)d_in[4];
    const float* W1b_l = (const float*)d_in[5];
    const float* b1b   = (const float*)d_in[6];
    const float* W1b_r = (const float*)d_in[7];
    const float* W2a_l = (const float*)d_in[8];
    const float* b2a   = (const float*)d_in[9];
    const float* W2a_r = (const float*)d_in[10];
    const float* W2b_l = (const float*)d_in[11];
    const float* b2b   = (const float*)d_in[12];
    const float* W2b_r = (const float*)d_in[13];
    const float* Wlin  = (const float*)d_in[14];
    const float* blin  = (const float*)d_in[15];

    const int N = in_sizes[0] / 128;
    const int E = in_sizes[1] / 2;
    const int S = (N + SLICE_W - 1) / SLICE_W;      // 98 slices @ N=50k
    const int B = (E + CHUNK - 1) / CHUNK;          // 391 chunks @ E=1.6M
    const int Bpad = (B + 15) & ~15;                // 400

    size_t o = 0;
    auto take = [&](size_t bytes) -> void* {
        void* p = (char*)d_ws + o;
        o += (bytes + 255) & ~(size_t)255;
        return p;
    };
    unsigned*       pe      = (unsigned*)take((size_t)E * 4);
    unsigned*       bedge   = (unsigned*)take((size_t)E * 4);
    int*            counts  = (int*)   take((size_t)S * Bpad * 4);
    int*            stotal  = (int*)   take((size_t)S * 4);
    int*            sbase   = (int*)   take((size_t)S * 4);
    int*            row_ptr = (int*)   take((size_t)(N + 1) * 4);
    float*          inv     = (float*) take((size_t)N * 4);
    unsigned short* adj     = (unsigned short*)take((size_t)E * 2);
    __half*         t       = (__half*)take((size_t)N * 64 * 2);
    __half*         u       = (__half*)take((size_t)N * 64 * 2);
    float*          hA      = (float*) take((size_t)N * 64 * 4);
    float*          hB      = (float*) take((size_t)N * 64 * 4);
    (void)ws_size; (void)n_in; (void)out_size;

    const int mb = (N + 63) / 64;                 // mm blocks
    const int gb = (N * 64 + 255) / 256;          // gather blocks (wave/node)

    // ---- build CSR: zero global atomics ----
    hist_pack<<<B, 256, 0, stream>>>(ei, pe, counts, E, S, Bpad);
    scan_cols<<<S, 512, 0, stream>>>(counts, stotal, B, Bpad);
    scan_slices<<<1, MAXS, 0, stream>>>(stotal, sbase, S);
    bucket_scatter<<<B, 256, 0, stream>>>(pe, counts, sbase, bedge, E, S, Bpad);
    csr_fill<<<S, 1024, 0, stream>>>(bedge, stotal, sbase, row_ptr, inv, adj, N, E);

    // ---- layer 1a: x[*,128] -> hA, relu ----
    mm_dual<128><<<mb, 256, 0, stream>>>(x, W1a_l, W1a_r, b1a, t, u, N);
    gather_fused<true><<<gb, 256, 0, stream>>>(t, adj, row_ptr, inv, u, hA, N);
    // ---- layer 1b: hA -> hB, relu ----
    mm_dual<64><<<mb, 256, 0, stream>>>(hA, W1b_l, W1b_r, b1b, t, u, N);
    gather_fused<true><<<gb, 256, 0, stream>>>(t, adj, row_ptr, inv, u, hB, N);
    // ---- layer 2a: hB -> hA, relu ----
    mm_dual<64><<<mb, 256, 0, stream>>>(hB, W2a_l, W2a_r, b2a, t, u, N);
    gather_fused<true><<<gb, 256, 0, stream>>>(t, adj, row_ptr, inv, u, hA, N);
    // ---- layer 2b: hA -> hB, no relu ----
    mm_dual<64><<<mb, 256, 0, stream>>>(hA, W2b_l, W2b_r, b2b, t, u, N);
    gather_fused<false><<<gb, 256, 0, stream>>>(t, adj, row_ptr, inv, u, hB, N);
    // ---- final linear ----
    mm_lin<<<mb, 256, 0, stream>>>(hB, Wlin, blin, (float*)d_out, N);
}